// Round 6
// baseline (866.554 us; speedup 1.0000x reference)
//
#include <hip/hip_runtime.h>

#define Df 64
#define NN 10000
#define EE 160000
#define RR 16
#define CC 512
#define CAP1 128
#define CAP2 2048
#define NB0 313              // ceil(10000/32) nodes, 32 nodes per 512-thr block
#define ND1 64               // 16*CAP1/32 delta1 blocks
#define NM2 256              // 16*CAP1/8 mark2 blocks
#define ND2 1024             // 16*CAP2/32 delta2 blocks
#define NSC 256              // 8192/32 score blocks

// ---------------- static device scratch ----------------
__device__ float g_h0[NN * Df];
__device__ float g_h1b[NN * Df];
__device__ float g_h2b[NN * Df];
__device__ __align__(16) float g_WsT0[4096];
__device__ __align__(16) float g_WnT0[4096];
__device__ __align__(16) float g_WsT1[4096];
__device__ __align__(16) float g_WnT1[4096];
__device__ __align__(16) float g_WeT[8192];
__device__ int g_cntI[NN], g_rowI[NN + 1], g_posI[NN], g_csrI[EE];
__device__ int g_cntO[NN], g_rowO[NN + 1], g_posO[NN], g_csrO[EE];
__device__ int g_mark1[RR][NN], g_mark2[RR][NN];
__device__ int g_n1[RR], g_n2[RR];
__device__ int g_list1[RR][CAP1], g_list2[RR][CAP2];
__device__ float g_d1[RR][CAP1][Df];
__device__ float g_d2[RR][CAP2][Df];
__device__ float g_score[RR * CC];

// ---------------- init: zero counters/marks + h0 + tiled-transpose weights ----------------
// W tile layout: WT[((k>>2)*64 + d)*4 + (k&3)] = W[k*64 + d]  (coalesced float4 per lane d)
__global__ void k_init(const float* __restrict__ coords, const float* __restrict__ We,
                       const float* __restrict__ be, const float* __restrict__ Ws0,
                       const float* __restrict__ Wn0, const float* __restrict__ Ws1,
                       const float* __restrict__ Wn1, const float* __restrict__ Wedge) {
    int i = blockIdx.x * 256 + threadIdx.x;
    if (i < NN * Df) {
        int n = i >> 6, d = i & 63;
        g_h0[i] = coords[2 * n] * We[d] + coords[2 * n + 1] * We[Df + d] + be[d];
    }
    if (i < NN) { g_cntI[i] = 0; g_cntO[i] = 0; }
    if (i < RR * NN) { (&g_mark1[0][0])[i] = 0; (&g_mark2[0][0])[i] = 0; }
    if (i < RR) { g_n1[i] = 0; g_n2[i] = 0; }
    if (i < 4096) {
        int k = i >> 6, d = i & 63, t = ((k >> 2) * 64 + d) * 4 + (k & 3);
        g_WsT0[t] = Ws0[i]; g_WnT0[t] = Wn0[i];
        g_WsT1[t] = Ws1[i]; g_WnT1[t] = Wn1[i];
    }
    if (i < 8192) {
        int k = i >> 6, d = i & 63;
        g_WeT[((k >> 2) * 64 + d) * 4 + (k & 3)] = Wedge[i];
    }
}

// ---------------- CSR build ----------------
__global__ void k_hist(const int* __restrict__ src, const int* __restrict__ dst) {
    int e = blockIdx.x * 256 + threadIdx.x;
    if (e < EE) { atomicAdd(&g_cntI[dst[e]], 1); atomicAdd(&g_cntO[src[e]], 1); }
}

__global__ void k_scan() {                       // grid 2 (dir), block 1024
    int dir = blockIdx.x;
    const int* cnt = dir ? g_cntO : g_cntI;
    int* row = dir ? g_rowO : g_rowI;
    int* pos = dir ? g_posO : g_posI;
    int t = threadIdx.x;
    int lane = t & 63, wv = t >> 6;              // 16 waves
    const int PER = 10;                          // 1024*10 >= NN
    int base = t * PER;
    int vals[PER]; int loc = 0;
#pragma unroll
    for (int k = 0; k < PER; k++) { int v = base + k; vals[k] = (v < NN) ? cnt[v] : 0; loc += vals[k]; }
    int sc = loc;                                // inclusive wave scan
#pragma unroll
    for (int off = 1; off < 64; off <<= 1) { int x = __shfl_up(sc, off, 64); if (lane >= off) sc += x; }
    __shared__ int wsum[16];
    if (lane == 63) wsum[wv] = sc;
    __syncthreads();
    if (t < 16) {
        int x = wsum[t]; int s2 = x;
#pragma unroll
        for (int off = 1; off < 16; off <<= 1) { int y = __shfl_up(s2, off, 16); if (t >= off) s2 += y; }
        wsum[t] = s2 - x;                        // exclusive wave offsets
    }
    __syncthreads();
    int run = wsum[wv] + (sc - loc);
#pragma unroll
    for (int k = 0; k < PER; k++) {
        int v = base + k;
        if (v < NN) { row[v] = run; pos[v] = run; run += vals[k]; }
    }
    if (t == 1023) row[NN] = run;
}

__global__ void k_fill(const int* __restrict__ src, const int* __restrict__ dst) {
    int e = blockIdx.x * 256 + threadIdx.x;
    if (e < EE) {
        int p = atomicAdd(&g_posI[dst[e]], 1);
        g_csrI[p] = src[e];
        int q = atomicAdd(&g_posO[src[e]], 1);
        g_csrO[q] = dst[e];
    }
}

// ---------------- claim helper ----------------
__device__ __forceinline__ void claim(int v, int* mark, int* n, int* list, int cap) {
    int old = atomicCAS(&mark[v], 0, -1);
    if (old == 0) {
        int p = atomicAdd(n, 1);
        if (p < cap) { list[p] = v; atomicExch(&mark[v], p + 1); }
        else atomicExch(&mark[v], 0);
    }
}

// ---------------- register-GEMM: wave computes 4 nodes x 64 dims ----------------
__device__ __forceinline__ void dense4(const float* __restrict__ WTs,
                                       const float* __restrict__ WTn, int lane, float bd,
                                       float hv0, float hv1, float hv2, float hv3,
                                       float ag0, float ag1, float ag2, float ag3,
                                       float& o0, float& o1, float& o2, float& o3) {
    float a0 = bd, a1 = bd, a2 = bd, a3 = bd;
#pragma unroll
    for (int c = 0; c < 2; c++) {
        float ws[32], wn[32];
#pragma unroll
        for (int m = 0; m < 8; m++) {
            float4 s4 = *(const float4*)&WTs[((c * 8 + m) * 64 + lane) * 4];
            float4 n4 = *(const float4*)&WTn[((c * 8 + m) * 64 + lane) * 4];
            ws[m*4+0] = s4.x; ws[m*4+1] = s4.y; ws[m*4+2] = s4.z; ws[m*4+3] = s4.w;
            wn[m*4+0] = n4.x; wn[m*4+1] = n4.y; wn[m*4+2] = n4.z; wn[m*4+3] = n4.w;
        }
#pragma unroll
        for (int kk = 0; kk < 32; kk++) {
            int k = c * 32 + kk;
            a0 += __shfl(hv0, k, 64) * ws[kk] + __shfl(ag0, k, 64) * wn[kk];
            a1 += __shfl(hv1, k, 64) * ws[kk] + __shfl(ag1, k, 64) * wn[kk];
            a2 += __shfl(hv2, k, 64) * ws[kk] + __shfl(ag2, k, 64) * wn[kk];
            a3 += __shfl(hv3, k, 64) * ws[kk] + __shfl(ag3, k, 64) * wn[kk];
        }
    }
    o0 = a0; o1 = a1; o2 = a2; o3 = a3;
}

__device__ __forceinline__ void base_quad(const float* __restrict__ hin,
                                          float* __restrict__ hout,
                                          const float* __restrict__ WTs,
                                          const float* __restrict__ WTn,
                                          const float* __restrict__ bias,
                                          int v0, int lane) {
    float hv[4], ag[4];
#pragma unroll
    for (int i = 0; i < 4; i++) {
        int v = v0 + i;
        if (v < NN) {
            int a0 = g_rowI[v], a1 = g_rowI[v + 1];
            float s = 0.f;
            for (int e = a0; e < a1; e++) s += hin[g_csrI[e] * Df + lane];
            hv[i] = hin[v * Df + lane];
            ag[i] = s / fmaxf((float)(a1 - a0), 1.f);
        } else { hv[i] = 0.f; ag[i] = 0.f; }
    }
    float o0, o1, o2, o3;
    dense4(WTs, WTn, lane, bias[lane], hv[0], hv[1], hv[2], hv[3],
           ag[0], ag[1], ag[2], ag[3], o0, o1, o2, o3);
    float o[4] = {o0, o1, o2, o3};
#pragma unroll
    for (int i = 0; i < 4; i++) {
        int v = v0 + i;
        if (v < NN) hout[v * Df + lane] = fmaxf(o[i], 0.f) + hv[i];
    }
}

// ---------------- phase 1: baseline layer 0 + mark1 ----------------
__global__ __launch_bounds__(512) void k_phase1(const int* __restrict__ removal,
                                                const float* __restrict__ b0) {
    int b = blockIdx.x, tid = threadIdx.x, lane = tid & 63, w = tid >> 6;
    if (b < NB0) {
        base_quad(g_h0, g_h1b, g_WsT0, g_WnT0, b0, b * 32 + w * 4, lane);
    } else {
        int ri = b - NB0;
        int r = removal[ri];
        if (tid == 0) claim(r, g_mark1[ri], &g_n1[ri], g_list1[ri], CAP1);
        int s0 = g_rowO[r], s1 = g_rowO[r + 1];
        for (int i = s0 + tid; i < s1; i += 512)
            claim(g_csrO[i], g_mark1[ri], &g_n1[ri], g_list1[ri], CAP1);
    }
}

// ---------------- phase 2: baseline layer 1 + delta1 + mark2 ----------------
__global__ __launch_bounds__(512) void k_phase2(const int* __restrict__ removal,
                                                const float* __restrict__ b0,
                                                const float* __restrict__ b1) {
    int b = blockIdx.x, tid = threadIdx.x, lane = tid & 63, w = tid >> 6;
    if (b < NB0) {
        base_quad(g_h1b, g_h2b, g_WsT1, g_WnT1, b1, b * 32 + w * 4, lane);
    } else if (b < NB0 + ND1) {
        int rel = b - NB0;
        int gs0 = rel * 32;
        int ri = gs0 >> 7;                       // CAP1=128 slots per removal
        int n1 = g_n1[ri];
        if ((gs0 & 127) >= n1) return;
        int r = removal[ri];
        int gs = gs0 + w * 4;
        float hv[4], ag[4]; int act[4];
#pragma unroll
        for (int i = 0; i < 4; i++) {
            int j = (gs + i) & 127;
            if (j < n1) {
                int v = g_list1[ri][j]; act[i] = 1;
                int a0 = g_rowI[v], a1 = g_rowI[v + 1];
                float s = 0.f; int c2 = 0;
                if (v != r) {
                    for (int e = a0; e < a1; e++) {
                        int sc = g_csrI[e];
                        if (sc != r) { s += g_h0[sc * Df + lane]; c2++; }
                    }
                }
                hv[i] = g_h0[v * Df + lane];
                ag[i] = s / fmaxf((float)c2, 1.f);
            } else { act[i] = 0; hv[i] = 0.f; ag[i] = 0.f; }
        }
        float o0, o1, o2, o3;
        dense4(g_WsT0, g_WnT0, lane, b0[lane], hv[0], hv[1], hv[2], hv[3],
               ag[0], ag[1], ag[2], ag[3], o0, o1, o2, o3);
        float o[4] = {o0, o1, o2, o3};
#pragma unroll
        for (int i = 0; i < 4; i++)
            if (act[i]) { int j = (gs + i) & 127; g_d1[ri][j][lane] = fmaxf(o[i], 0.f) + hv[i]; }
    } else {
        int rel = b - NB0 - ND1;
        int gs = rel * 8 + w;                    // one slot per wave
        int ri = gs >> 7, j = gs & 127;
        if (j < g_n1[ri]) {
            int u = g_list1[ri][j];
            if (lane == 0) claim(u, g_mark2[ri], &g_n2[ri], g_list2[ri], CAP2);
            int s0 = g_rowO[u], s1 = g_rowO[u + 1];
            for (int i = s0 + lane; i < s1; i += 64)
                claim(g_csrO[i], g_mark2[ri], &g_n2[ri], g_list2[ri], CAP2);
        }
    }
}

// ---------------- phase 3: delta2 ----------------
__global__ __launch_bounds__(512) void k_delta2(const int* __restrict__ removal,
                                                const float* __restrict__ b1) {
    int b = blockIdx.x, tid = threadIdx.x, lane = tid & 63, w = tid >> 6;
    int gs0 = b * 32;
    int ri = gs0 >> 11;                          // CAP2=2048 slots per removal
    int n2 = g_n2[ri];
    if ((gs0 & 2047) >= n2) return;
    int r = removal[ri];
    const int* mk1 = g_mark1[ri];
    int gs = gs0 + w * 4;
    float hv[4], ag[4]; int act[4];
#pragma unroll
    for (int i = 0; i < 4; i++) {
        int j = (gs + i) & 2047;
        if (j < n2) {
            int v = g_list2[ri][j]; act[i] = 1;
            int a0 = g_rowI[v], a1 = g_rowI[v + 1];
            float s = 0.f; int c2 = 0;
            if (v != r) {
                for (int e = a0; e < a1; e++) {
                    int sc = g_csrI[e];
                    if (sc != r) {
                        int m = mk1[sc];
                        const float* hp = (m > 0) ? &g_d1[ri][m - 1][0] : &g_h1b[sc * Df];
                        s += hp[lane]; c2++;
                    }
                }
            }
            int mv = mk1[v];
            hv[i] = (mv > 0) ? g_d1[ri][mv - 1][lane] : g_h1b[v * Df + lane];
            ag[i] = s / fmaxf((float)c2, 1.f);
        } else { act[i] = 0; hv[i] = 0.f; ag[i] = 0.f; }
    }
    float o0, o1, o2, o3;
    dense4(g_WsT1, g_WnT1, lane, b1[lane], hv[0], hv[1], hv[2], hv[3],
           ag[0], ag[1], ag[2], ag[3], o0, o1, o2, o3);
    float o[4] = {o0, o1, o2, o3};
#pragma unroll
    for (int i = 0; i < 4; i++)
        if (act[i]) { int j = (gs + i) & 2047; g_d2[ri][j][lane] = fmaxf(o[i], 0.f) + hv[i]; }
}

// ---------------- phase 4: edge scoring (wave = 4 edges) ----------------
__global__ __launch_bounds__(512) void k_score(const int* __restrict__ conn,
        const int* __restrict__ removal, const int* __restrict__ esrc,
        const int* __restrict__ edst, const float* __restrict__ be,
        const float* __restrict__ Wsc, const float* __restrict__ bsc) {
    int b = blockIdx.x, tid = threadIdx.x, lane = tid & 63, w = tid >> 6;
    int ge0 = b * 32 + w * 4;                    // global edge id = ri*CC + c
    int ri = ge0 >> 9;
    int r = removal[ri];
    const int* mk2 = g_mark2[ri];
    float hs[4], hd[4];
#pragma unroll
    for (int i = 0; i < 4; i++) {
        int e = conn[ge0 + i];
        int s = esrc[e], t = edst[e];
        int ms = mk2[s], md = mk2[t];
        hs[i] = (ms > 0) ? g_d2[ri][ms - 1][lane] : g_h2b[s * Df + lane];
        hd[i] = (md > 0) ? g_d2[ri][md - 1][lane] : g_h2b[t * Df + lane];
    }
    float bd = be[lane];
    float a0 = bd, a1 = bd, a2 = bd, a3 = bd;
#pragma unroll
    for (int ch = 0; ch < 4; ch++) {
        float wv[32];
#pragma unroll
        for (int m = 0; m < 8; m++) {
            float4 t4 = *(const float4*)&g_WeT[((ch * 8 + m) * 64 + lane) * 4];
            wv[m*4+0] = t4.x; wv[m*4+1] = t4.y; wv[m*4+2] = t4.z; wv[m*4+3] = t4.w;
        }
#pragma unroll
        for (int kk = 0; kk < 32; kk++) {
            int k = ch * 32 + kk;
            float x0, x1, x2, x3;
            if (ch < 2) {
                x0 = __shfl(hs[0], k, 64); x1 = __shfl(hs[1], k, 64);
                x2 = __shfl(hs[2], k, 64); x3 = __shfl(hs[3], k, 64);
            } else {
                x0 = __shfl(hd[0], k - 64, 64); x1 = __shfl(hd[1], k - 64, 64);
                x2 = __shfl(hd[2], k - 64, 64); x3 = __shfl(hd[3], k - 64, 64);
            }
            a0 += x0 * wv[kk]; a1 += x1 * wv[kk]; a2 += x2 * wv[kk]; a3 += x3 * wv[kk];
        }
    }
    float wj = Wsc[Df + lane];
    float t0 = fmaxf(a0, 0.f) * wj, t1 = fmaxf(a1, 0.f) * wj;
    float t2 = fmaxf(a2, 0.f) * wj, t3 = fmaxf(a3, 0.f) * wj;
    float u = g_h0[r * Df + lane] * Wsc[lane];
#pragma unroll
    for (int off = 32; off > 0; off >>= 1) {
        t0 += __shfl_xor(t0, off, 64); t1 += __shfl_xor(t1, off, 64);
        t2 += __shfl_xor(t2, off, 64); t3 += __shfl_xor(t3, off, 64);
        u  += __shfl_xor(u,  off, 64);
    }
    if (lane == 0) {
        float bb = bsc[0];
        g_score[ge0 + 0] = t0 + u + bb;
        g_score[ge0 + 1] = t1 + u + bb;
        g_score[ge0 + 2] = t2 + u + bb;
        g_score[ge0 + 3] = t3 + u + bb;
    }
}

// ---------------- softmax over C per removal ----------------
__global__ void k_softmax(float* __restrict__ out) {
    int r = blockIdx.x;
    int t = threadIdx.x;                        // 256 threads, 2 elems each
    float v0 = g_score[r * CC + t];
    float v1 = g_score[r * CC + 256 + t];
    __shared__ float red[256];
    red[t] = fmaxf(v0, v1);
    __syncthreads();
    for (int off = 128; off > 0; off >>= 1) {
        if (t < off) red[t] = fmaxf(red[t], red[t + off]);
        __syncthreads();
    }
    float mx = red[0];
    __syncthreads();
    float e0 = expf(v0 - mx), e1 = expf(v1 - mx);
    red[t] = e0 + e1;
    __syncthreads();
    for (int off = 128; off > 0; off >>= 1) {
        if (t < off) red[t] += red[t + off];
        __syncthreads();
    }
    float inv = 1.f / red[0];
    out[r * CC + t] = e0 * inv;
    out[r * CC + 256 + t] = e1 * inv;
}

extern "C" void kernel_launch(void* const* d_in, const int* in_sizes, int n_in,
                              void* d_out, int out_size, void* d_ws, size_t ws_size,
                              hipStream_t stream) {
    const float* coords   = (const float*)d_in[0];
    const float* W_emb    = (const float*)d_in[1];
    const float* b_emb    = (const float*)d_in[2];
    const float* W_self0  = (const float*)d_in[3];
    const float* W_neigh0 = (const float*)d_in[4];
    const float* b_gnn0   = (const float*)d_in[5];
    const float* W_self1  = (const float*)d_in[6];
    const float* W_neigh1 = (const float*)d_in[7];
    const float* b_gnn1   = (const float*)d_in[8];
    const float* W_edge   = (const float*)d_in[9];
    const float* b_edge   = (const float*)d_in[10];
    const float* W_score  = (const float*)d_in[11];
    const float* b_score  = (const float*)d_in[12];
    const int* esrc       = (const int*)d_in[13];
    const int* edst       = (const int*)d_in[14];
    const int* removal    = (const int*)d_in[15];
    const int* conn       = (const int*)d_in[16];

    k_init<<<2500, 256, 0, stream>>>(coords, W_emb, b_emb, W_self0, W_neigh0,
                                     W_self1, W_neigh1, W_edge);
    k_hist<<<625, 256, 0, stream>>>(esrc, edst);
    k_scan<<<2, 1024, 0, stream>>>();
    k_fill<<<625, 256, 0, stream>>>(esrc, edst);

    k_phase1<<<NB0 + RR, 512, 0, stream>>>(removal, b_gnn0);
    k_phase2<<<NB0 + ND1 + NM2, 512, 0, stream>>>(removal, b_gnn0, b_gnn1);
    k_delta2<<<ND2, 512, 0, stream>>>(removal, b_gnn1);

    k_score<<<NSC, 512, 0, stream>>>(conn, removal, esrc, edst,
                                     b_edge, W_score, b_score);
    k_softmax<<<RR, 256, 0, stream>>>((float*)d_out);
}

// Round 7
// 178.479 us; speedup vs baseline: 4.8552x; 4.8552x over previous
//
#include <hip/hip_runtime.h>

#define Df 64
#define NN 10000
#define EE 160000
#define RR 16
#define CC 512
#define CAP1 128
#define CAP2 2048
#define NBASE 625            // 10000 nodes / 16 per block

// ---------------- static device scratch ----------------
__device__ float g_h0[NN * Df];
__device__ float g_h1b[NN * Df];
__device__ float g_h2b[NN * Df];
__device__ __align__(16) float g_WsT0[4096];   // tiled: ((k>>2)*64+d)*4+(k&3)
__device__ __align__(16) float g_WnT0[4096];
__device__ __align__(16) float g_WsT1[4096];
__device__ __align__(16) float g_WnT1[4096];
__device__ int g_cntI[NN], g_rowI[NN + 1], g_posI[NN], g_csrI[EE];
__device__ int g_cntO[NN], g_rowO[NN + 1], g_posO[NN], g_csrO[EE];
__device__ int g_mark1[RR][NN], g_mark2[RR][NN];
__device__ int g_n1[RR], g_n2[RR];
__device__ int g_list1[RR][CAP1], g_list2[RR][CAP2];
__device__ float g_d1[RR][CAP1][Df];
__device__ float g_d2[RR][CAP2][Df];
__device__ float g_score[RR * CC];

// ---------------- init: zero counters/marks + h0 + tiled-transpose weights ----------------
__global__ void k_init(const float* __restrict__ coords, const float* __restrict__ We,
                       const float* __restrict__ be, const float* __restrict__ Ws0,
                       const float* __restrict__ Wn0, const float* __restrict__ Ws1,
                       const float* __restrict__ Wn1) {
    int i = blockIdx.x * 256 + threadIdx.x;
    if (i < NN * Df) {
        int n = i >> 6, d = i & 63;
        g_h0[i] = coords[2 * n] * We[d] + coords[2 * n + 1] * We[Df + d] + be[d];
    }
    if (i < NN) { g_cntI[i] = 0; g_cntO[i] = 0; }
    if (i < RR * NN) { (&g_mark1[0][0])[i] = 0; (&g_mark2[0][0])[i] = 0; }
    if (i < RR) { g_n1[i] = 0; g_n2[i] = 0; }
    if (i < 4096) {
        int k = i >> 6, d = i & 63, t = ((k >> 2) * 64 + d) * 4 + (k & 3);
        g_WsT0[t] = Ws0[i]; g_WnT0[t] = Wn0[i];
        g_WsT1[t] = Ws1[i]; g_WnT1[t] = Wn1[i];
    }
}

// ---------------- CSR build ----------------
__global__ void k_hist(const int* __restrict__ src, const int* __restrict__ dst) {
    int e = blockIdx.x * 256 + threadIdx.x;
    if (e < EE) { atomicAdd(&g_cntI[dst[e]], 1); atomicAdd(&g_cntO[src[e]], 1); }
}

__global__ void k_scan() {                       // grid 2 (dir), block 1024
    int dir = blockIdx.x;
    const int* cnt = dir ? g_cntO : g_cntI;
    int* row = dir ? g_rowO : g_rowI;
    int* pos = dir ? g_posO : g_posI;
    int t = threadIdx.x;
    int lane = t & 63, wv = t >> 6;              // 16 waves
    const int PER = 10;
    int base = t * PER;
    int vals[PER]; int loc = 0;
#pragma unroll
    for (int k = 0; k < PER; k++) { int v = base + k; vals[k] = (v < NN) ? cnt[v] : 0; loc += vals[k]; }
    int sc = loc;
#pragma unroll
    for (int off = 1; off < 64; off <<= 1) { int x = __shfl_up(sc, off, 64); if (lane >= off) sc += x; }
    __shared__ int wsum[16];
    if (lane == 63) wsum[wv] = sc;
    __syncthreads();
    if (t < 16) {
        int x = wsum[t]; int s2 = x;
#pragma unroll
        for (int off = 1; off < 16; off <<= 1) { int y = __shfl_up(s2, off, 16); if (t >= off) s2 += y; }
        wsum[t] = s2 - x;
    }
    __syncthreads();
    int run = wsum[wv] + (sc - loc);
#pragma unroll
    for (int k = 0; k < PER; k++) {
        int v = base + k;
        if (v < NN) { row[v] = run; pos[v] = run; run += vals[k]; }
    }
    if (t == 1023) row[NN] = run;
}

__global__ void k_fill(const int* __restrict__ src, const int* __restrict__ dst) {
    int e = blockIdx.x * 256 + threadIdx.x;
    if (e < EE) {
        int p = atomicAdd(&g_posI[dst[e]], 1);
        g_csrI[p] = src[e];
        int q = atomicAdd(&g_posO[src[e]], 1);
        g_csrO[q] = dst[e];
    }
}

// ---------------- claim helper ----------------
__device__ __forceinline__ void claim(int v, int* mark, int* n, int* list, int cap) {
    int old = atomicCAS(&mark[v], 0, -1);
    if (old == 0) {
        int p = atomicAdd(n, 1);
        if (p < cap) { list[p] = v; atomicExch(&mark[v], p + 1); }
        else atomicExch(&mark[v], 0);
    }
}

// ---------------- baseline layer: LDS-staged W, 4 nodes/wave, 16 nodes/block ----------------
// layer 0 launch has 16 extra blocks doing mark1.
__global__ __launch_bounds__(256) void k_base(int layer, const float* __restrict__ bias,
                                              const int* __restrict__ removal) {
    __shared__ float4 lws[1024];                 // 16 KB
    __shared__ float4 lwn[1024];                 // 16 KB
    __shared__ float hb_s[4][4][Df];             // 4 KB  per-wave node broadcasts
    __shared__ float ab_s[4][4][Df];             // 4 KB
    int tid = threadIdx.x, lane = tid & 63, w = tid >> 6;
    int b = blockIdx.x;

    if (b >= NBASE) {                            // mark1 role (layer-0 launch only)
        int ri = b - NBASE;
        int r = removal[ri];
        if (tid == 0) claim(r, g_mark1[ri], &g_n1[ri], g_list1[ri], CAP1);
        int s0 = g_rowO[r], s1 = g_rowO[r + 1];
        for (int i = s0 + tid; i < s1; i += 256)
            claim(g_csrO[i], g_mark1[ri], &g_n1[ri], g_list1[ri], CAP1);
        return;
    }

    const float* hin = layer ? g_h1b : g_h0;
    float* hout      = layer ? g_h2b : g_h1b;
    const float4* WsT4 = (const float4*)(layer ? g_WsT1 : g_WsT0);
    const float4* WnT4 = (const float4*)(layer ? g_WnT1 : g_WnT0);

    for (int i = tid; i < 1024; i += 256) { lws[i] = WsT4[i]; lwn[i] = WnT4[i]; }
    __syncthreads();

    int v0 = b * 16 + w * 4;
    float hv[4], ag[4];
#pragma unroll
    for (int i = 0; i < 4; i++) {
        int v = v0 + i;
        int a0 = g_rowI[v], a1 = g_rowI[v + 1];
        float s = 0.f;
        for (int e = a0; e < a1; e++) s += hin[g_csrI[e] * Df + lane];
        hv[i] = hin[v * Df + lane];
        ag[i] = s / fmaxf((float)(a1 - a0), 1.f);
        hb_s[w][i][lane] = hv[i];
        ab_s[w][i][lane] = ag[i];
    }
    const float4* hb4 = (const float4*)&hb_s[w][0][0];   // [4][16]
    const float4* ab4 = (const float4*)&ab_s[w][0][0];

    float bd = bias[lane];
    float acc[4] = {bd, bd, bd, bd};
#pragma unroll
    for (int kq = 0; kq < 16; kq++) {
        float4 ws = lws[kq * 64 + lane];
        float4 wn = lwn[kq * 64 + lane];
#pragma unroll
        for (int i = 0; i < 4; i++) {
            float4 h4 = hb4[i * 16 + kq];
            float4 a4 = ab4[i * 16 + kq];
            acc[i] += h4.x * ws.x + h4.y * ws.y + h4.z * ws.z + h4.w * ws.w
                    + a4.x * wn.x + a4.y * wn.y + a4.z * wn.z + a4.w * wn.w;
        }
    }
#pragma unroll
    for (int i = 0; i < 4; i++)
        hout[(v0 + i) * Df + lane] = fmaxf(acc[i], 0.f) + hv[i];
}

// ---------------- delta1 + mark2 (one launch, grid (RR, 2*CAP1), block 64) ----------------
__global__ void k_d1m2(const int* __restrict__ removal_idx,
                       const float* __restrict__ Ws, const float* __restrict__ Wn,
                       const float* __restrict__ b) {
    int ri = blockIdx.x, jy = blockIdx.y;
    if (jy >= CAP1) {                            // mark2 role
        int j = jy - CAP1;
        if (j >= g_n1[ri]) return;
        int u = g_list1[ri][j];
        int lane = threadIdx.x;
        if (lane == 0) claim(u, g_mark2[ri], &g_n2[ri], g_list2[ri], CAP2);
        int s0 = g_rowO[u], s1 = g_rowO[u + 1];
        for (int i = s0 + lane; i < s1; i += 64)
            claim(g_csrO[i], g_mark2[ri], &g_n2[ri], g_list2[ri], CAP2);
        return;
    }
    int j = jy;
    if (j >= g_n1[ri]) return;
    int v = g_list1[ri][j];
    int r = removal_idx[ri];
    int d = threadIdx.x;

    float aggd = 0.f; int cnt = 0;
    if (v != r) {
        int s0 = g_rowI[v], s1 = g_rowI[v + 1];
        for (int i = s0; i < s1; i++) {
            int s = g_csrI[i];
            if (s == r) continue;
            aggd += g_h0[s * Df + d];
            cnt++;
        }
    }
    float aggn = aggd / fmaxf((float)cnt, 1.f);

    __shared__ float hv_s[Df], ag_s[Df];
    float hv = g_h0[v * Df + d];
    hv_s[d] = hv; ag_s[d] = aggn;
    __syncthreads();

    float acc = b[d];
#pragma unroll 16
    for (int k = 0; k < Df; k++)
        acc += hv_s[k] * Ws[k * Df + d] + ag_s[k] * Wn[k * Df + d];

    g_d1[ri][j][d] = fmaxf(acc, 0.f) + hv;
}

// ---------------- delta2: grid (RR, CAP2), block 64 ----------------
__global__ void k_delta2(const int* __restrict__ removal_idx,
                         const float* __restrict__ Ws, const float* __restrict__ Wn,
                         const float* __restrict__ b) {
    int ri = blockIdx.x, j = blockIdx.y;
    if (j >= g_n2[ri]) return;
    int v = g_list2[ri][j];
    int r = removal_idx[ri];
    int d = threadIdx.x;
    const int* mk1 = g_mark1[ri];

    float aggd = 0.f; int cnt = 0;
    if (v != r) {
        int s0 = g_rowI[v], s1 = g_rowI[v + 1];
        for (int i = s0; i < s1; i++) {
            int s = g_csrI[i];
            if (s == r) continue;
            int m = mk1[s];
            const float* hp = (m > 0) ? &g_d1[ri][m - 1][0] : &g_h1b[s * Df];
            aggd += hp[d];
            cnt++;
        }
    }
    float aggn = aggd / fmaxf((float)cnt, 1.f);

    __shared__ float hv_s[Df], ag_s[Df];
    int mv = mk1[v];
    float hv = (mv > 0) ? g_d1[ri][mv - 1][d] : g_h1b[v * Df + d];
    hv_s[d] = hv; ag_s[d] = aggn;
    __syncthreads();

    float acc = b[d];
#pragma unroll 16
    for (int k = 0; k < Df; k++)
        acc += hv_s[k] * Ws[k * Df + d] + ag_s[k] * Wn[k * Df + d];

    g_d2[ri][j][d] = fmaxf(acc, 0.f) + hv;
}

// ---------------- edge scoring: grid (CC, RR), block 64 ----------------
__global__ void k_score(const int* __restrict__ conn, const int* __restrict__ removal_idx,
                        const int* __restrict__ esrc, const int* __restrict__ edst,
                        const float* __restrict__ We, const float* __restrict__ be,
                        const float* __restrict__ Wsc, const float* __restrict__ bsc) {
    int c = blockIdx.x, ri = blockIdx.y;
    int r = removal_idx[ri];
    int e = conn[ri * CC + c];
    int s = esrc[e], dd = edst[e];
    int j = threadIdx.x;

    int ms = g_mark2[ri][s], md = g_mark2[ri][dd];
    const float* hsp = (ms > 0) ? &g_d2[ri][ms - 1][0] : &g_h2b[s * Df];
    const float* hdp = (md > 0) ? &g_d2[ri][md - 1][0] : &g_h2b[dd * Df];

    __shared__ float hs[Df], hd[Df];
    hs[j] = hsp[j];
    hd[j] = hdp[j];
    __syncthreads();

    float acc = be[j];
#pragma unroll 16
    for (int k = 0; k < Df; k++)
        acc += hs[k] * We[k * Df + j] + hd[k] * We[(Df + k) * Df + j];
    float ef = fmaxf(acc, 0.f);

    float part = ef * Wsc[Df + j] + g_h0[r * Df + j] * Wsc[j];
#pragma unroll
    for (int off = 32; off > 0; off >>= 1) part += __shfl_xor(part, off);
    if (j == 0) g_score[ri * CC + c] = part + bsc[0];
}

// ---------------- softmax over C per removal ----------------
__global__ void k_softmax(float* __restrict__ out) {
    int r = blockIdx.x;
    int t = threadIdx.x;
    float v0 = g_score[r * CC + t];
    float v1 = g_score[r * CC + 256 + t];
    __shared__ float red[256];
    red[t] = fmaxf(v0, v1);
    __syncthreads();
    for (int off = 128; off > 0; off >>= 1) {
        if (t < off) red[t] = fmaxf(red[t], red[t + off]);
        __syncthreads();
    }
    float mx = red[0];
    __syncthreads();
    float e0 = expf(v0 - mx), e1 = expf(v1 - mx);
    red[t] = e0 + e1;
    __syncthreads();
    for (int off = 128; off > 0; off >>= 1) {
        if (t < off) red[t] += red[t + off];
        __syncthreads();
    }
    float inv = 1.f / red[0];
    out[r * CC + t] = e0 * inv;
    out[r * CC + 256 + t] = e1 * inv;
}

extern "C" void kernel_launch(void* const* d_in, const int* in_sizes, int n_in,
                              void* d_out, int out_size, void* d_ws, size_t ws_size,
                              hipStream_t stream) {
    const float* coords   = (const float*)d_in[0];
    const float* W_emb    = (const float*)d_in[1];
    const float* b_emb    = (const float*)d_in[2];
    const float* W_self0  = (const float*)d_in[3];
    const float* W_neigh0 = (const float*)d_in[4];
    const float* b_gnn0   = (const float*)d_in[5];
    const float* W_self1  = (const float*)d_in[6];
    const float* W_neigh1 = (const float*)d_in[7];
    const float* b_gnn1   = (const float*)d_in[8];
    const float* W_edge   = (const float*)d_in[9];
    const float* b_edge   = (const float*)d_in[10];
    const float* W_score  = (const float*)d_in[11];
    const float* b_score  = (const float*)d_in[12];
    const int* esrc       = (const int*)d_in[13];
    const int* edst       = (const int*)d_in[14];
    const int* removal    = (const int*)d_in[15];
    const int* conn       = (const int*)d_in[16];

    k_init<<<2500, 256, 0, stream>>>(coords, W_emb, b_emb, W_self0, W_neigh0,
                                     W_self1, W_neigh1);
    k_hist<<<625, 256, 0, stream>>>(esrc, edst);
    k_scan<<<2, 1024, 0, stream>>>();
    k_fill<<<625, 256, 0, stream>>>(esrc, edst);

    k_base<<<NBASE + RR, 256, 0, stream>>>(0, b_gnn0, removal);   // base layer 0 + mark1
    k_base<<<NBASE, 256, 0, stream>>>(1, b_gnn1, removal);        // base layer 1
    k_d1m2<<<dim3(RR, 2 * CAP1), 64, 0, stream>>>(removal, W_self0, W_neigh0, b_gnn0);
    k_delta2<<<dim3(RR, CAP2), 64, 0, stream>>>(removal, W_self1, W_neigh1, b_gnn1);

    k_score<<<dim3(CC, RR), 64, 0, stream>>>(conn, removal, esrc, edst,
                                             W_edge, b_edge, W_score, b_score);
    k_softmax<<<RR, 256, 0, stream>>>((float*)d_out);
}